// Round 15
// baseline (74.664 us; speedup 1.0000x reference)
//
#include <hip/hip_runtime.h>
#include <stdint.h>

#define BB 8
#define NN 2048
#define IND 10
#define QK 32

typedef float f32x4 __attribute__((ext_vector_type(4)));

// Kernel 1: q[b][n][qd] = sum_d s[b,n,d]*Wq[qd,d]; k likewise.
// kt permuted for kernel 2's read: attn thread (wave w, lane i) owns cols
//   {512w + 4i + j : j=0..3} and {512w + 256 + 4i + j : j=0..3}.
// kt float4 index: (b*4+w)*4096 + (ev*8+jc)*64 + i, component c (qd=4ev+c).
__global__ __launch_bounds__(256) void qk_kernel(
    const float* __restrict__ s,
    const float* __restrict__ Wq, const float* __restrict__ Wk,
    float* __restrict__ q_ws, float* __restrict__ kt_ws) {
  int t = blockIdx.x * 256 + threadIdx.x;      // 0 .. B*N*QK-1 (exact)
  int b  = t >> 16;                            // N*QK = 65536
  int n  = (t >> 5) & (NN - 1);
  int qd = t & 31;
  const float* srow = s + (size_t)(b * NN + n) * IND;
  float acq = 0.f, ack = 0.f;
#pragma unroll
  for (int d = 0; d < IND; ++d) {
    float sv = srow[d];
    acq = fmaf(sv, Wq[qd * IND + d], acq);
    ack = fmaf(sv, Wk[qd * IND + d], ack);
  }
  q_ws[(size_t)(b * NN + n) * QK + qd] = acq;
  int w  = n >> 9;                 // wave (512 cols each)
  int m  = n & 511;
  int i  = (m & 255) >> 2;         // lane
  int jc = ((m < 256) ? 0 : 4) + (m & 3);
  int ev = qd >> 2, c = qd & 3;
  kt_ws[(((size_t)(b * 4 + w) * 4096) + (ev * 8 + jc) * 64 + i) * 4 + c] = ack;
}

// Kernel 2: one block = (batch, 8 rows), 256 threads. Thread (w,lane) owns
// cols {512w+4*lane+j} and {512w+256+4*lane+j}, j=0..3, for all 8 rows.
// GEMM: R13's ka/kb k-double-buffer. Epilogue: all 16 G float4s prefetched
// into named registers, NON-TEMPORAL (G is stream-once; keeps kt L2-hot),
// between two sched fences so the loads can't hoist into the GEMM and the
// math can't rise above the loads. __launch_bounds__(256,2) raises the VGPR
// cap to 256 so the allocator actually MATERIALIZES the 64-reg prefetch
// (R14: default heuristic sank it, VGPR stuck at 100). Peak pressure ~150
// in GEMM, ~140 in epilogue -> no spill possible under the cap; allowed
// occupancy (8 waves/CU) still >= the 6 waves/CU R14 achieved.
__global__ __launch_bounds__(256, 2) void attn_kernel(
    const float* __restrict__ G,
    const float* __restrict__ q_ws, const float* __restrict__ kt_ws,
    float* __restrict__ out) {
  const int tid = threadIdx.x;
  const int b = blockIdx.y;
  const int r0 = blockIdx.x * 8;
  const int w = tid >> 6, lane = tid & 63;

  __shared__ float q_lds[4][256];  // wave-private q tile copies (1 KB/wave)
  __shared__ float red[4][8];

  // ---- wave-private q copy (8 rows x 32 = 256 contiguous floats) ----
  {
    const float* qb = q_ws + ((size_t)b * NN + r0) * QK;
    *(float4*)&q_lds[w][4 * lane] = *(const float4*)&qb[4 * lane];
  }

  // ---- GEMM: acc[r][j] = q[r0+r] . k[col(w,lane,j)] ----
  float acc[8][8];
#pragma unroll
  for (int r = 0; r < 8; ++r)
#pragma unroll
    for (int j = 0; j < 8; ++j) acc[r][j] = 0.f;

  const float4* kt =
      (const float4*)kt_ws + (size_t)(b * 4 + w) * 4096 + lane;

  float4 ka[8], kb[8];
#pragma unroll
  for (int j = 0; j < 8; ++j) ka[j] = kt[j * 64];  // ev=0, lane-coalesced

#pragma unroll
  for (int ev = 0; ev < 8; ++ev) {
    if (ev < 7) {
#pragma unroll
      for (int j = 0; j < 8; ++j) kb[j] = kt[((ev + 1) * 8 + j) * 64];
    }
#pragma unroll
    for (int r = 0; r < 8; ++r) {
      float q4[4];
      *(float4*)q4 = *(const float4*)&q_lds[w][r * 32 + ev * 4];  // broadcast
#pragma unroll
      for (int j = 0; j < 8; ++j) {
        acc[r][j] = fmaf(q4[0], ka[j].x, acc[r][j]);
        acc[r][j] = fmaf(q4[1], ka[j].y, acc[r][j]);
        acc[r][j] = fmaf(q4[2], ka[j].z, acc[r][j]);
        acc[r][j] = fmaf(q4[3], ka[j].w, acc[r][j]);
      }
    }
#pragma unroll
    for (int j = 0; j < 8; ++j) ka[j] = kb[j];  // renamed away by unroll
  }

  __builtin_amdgcn_sched_barrier(0);  // fence: G loads stay below (post-GEMM)

  // ---- epilogue: prefetch ALL G into registers (non-temporal) ----
  const float* gb = G + ((size_t)b * NN + r0) * NN + 512 * w + 4 * lane;
  f32x4 g0[8], g1[8];
#pragma unroll
  for (int r = 0; r < 8; ++r) {
    g0[r] = __builtin_nontemporal_load((const f32x4*)(gb + (size_t)r * NN));
    g1[r] =
        __builtin_nontemporal_load((const f32x4*)(gb + (size_t)r * NN + 256));
  }
  __builtin_amdgcn_sched_barrier(0);  // fence: math stays below the loads

  float rsum[8];
#pragma unroll
  for (int r = 0; r < 8; ++r) {
    float gg[8];
    *(f32x4*)&gg[0] = g0[r];
    *(f32x4*)&gg[4] = g1[r];
    float sum = 0.f;
#pragma unroll
    for (int j = 0; j < 8; ++j) {
      float v = acc[r][j];
      v = v * v * gg[j];
      acc[r][j] = v;
      sum += v;
    }
#pragma unroll
    for (int off = 32; off >= 1; off >>= 1) sum += __shfl_xor(sum, off, 64);
    rsum[r] = sum;
  }

  // ---- cross-wave reduce ----
  if ((tid & 63) == 0) {
#pragma unroll
    for (int r = 0; r < 8; ++r) red[w][r] = rsum[r];
  }
  __syncthreads();

  float inv[8];
#pragma unroll
  for (int r = 0; r < 8; ++r) {
    float total = red[0][r] + red[1][r] + red[2][r] + red[3][r];
    inv[r] = 1.0f / (total + 1e-6f);
  }

  // ---- scale + coalesced non-temporal store ----
  float* ob = out + ((size_t)b * NN + r0) * NN + 512 * w + 4 * lane;
#pragma unroll
  for (int r = 0; r < 8; ++r) {
    f32x4 o0, o1;
    o0.x = acc[r][0] * inv[r]; o0.y = acc[r][1] * inv[r];
    o0.z = acc[r][2] * inv[r]; o0.w = acc[r][3] * inv[r];
    o1.x = acc[r][4] * inv[r]; o1.y = acc[r][5] * inv[r];
    o1.z = acc[r][6] * inv[r]; o1.w = acc[r][7] * inv[r];
    __builtin_nontemporal_store(o0, (f32x4*)(ob + (size_t)r * NN));
    __builtin_nontemporal_store(o1, (f32x4*)(ob + (size_t)r * NN + 256));
  }
}

extern "C" void kernel_launch(void* const* d_in, const int* in_sizes, int n_in,
                              void* d_out, int out_size, void* d_ws, size_t ws_size,
                              hipStream_t stream) {
  const float* s  = (const float*)d_in[0];
  const float* G  = (const float*)d_in[1];
  const float* Wq = (const float*)d_in[2];
  const float* Wk = (const float*)d_in[3];
  float* out = (float*)d_out;

  float* q_ws  = (float*)d_ws;                       // B*N*QK floats = 2 MB
  float* kt_ws = q_ws + (size_t)BB * NN * QK;        // another 2 MB

  qk_kernel<<<(BB * NN * QK) / 256, 256, 0, stream>>>(s, Wq, Wk, q_ws, kt_ws);

  dim3 grid(NN / 8, BB);
  attn_kernel<<<grid, 256, 0, stream>>>(G, q_ws, kt_ws, out);
}

// Round 16
// 62.363 us; speedup vs baseline: 1.1972x; 1.1972x over previous
//
#include <hip/hip_runtime.h>
#include <stdint.h>

#define BB 8
#define NN 2048
#define IND 10
#define QK 32

typedef float f32x4 __attribute__((ext_vector_type(4)));

// Kernel 1: q[b][n][qd] = sum_d s[b,n,d]*Wq[qd,d]; k likewise.
// kt permuted for kernel 2's read: attn thread (wave w, lane i) owns cols
//   {512w + 4i + j : j=0..3} and {512w + 256 + 4i + j : j=0..3}.
// kt float4 index: (b*4+w)*4096 + (ev*8+jc)*64 + i, component c (qd=4ev+c).
__global__ __launch_bounds__(256) void qk_kernel(
    const float* __restrict__ s,
    const float* __restrict__ Wq, const float* __restrict__ Wk,
    float* __restrict__ q_ws, float* __restrict__ kt_ws) {
  int t = blockIdx.x * 256 + threadIdx.x;      // 0 .. B*N*QK-1 (exact)
  int b  = t >> 16;                            // N*QK = 65536
  int n  = (t >> 5) & (NN - 1);
  int qd = t & 31;
  const float* srow = s + (size_t)(b * NN + n) * IND;
  float acq = 0.f, ack = 0.f;
#pragma unroll
  for (int d = 0; d < IND; ++d) {
    float sv = srow[d];
    acq = fmaf(sv, Wq[qd * IND + d], acq);
    ack = fmaf(sv, Wk[qd * IND + d], ack);
  }
  q_ws[(size_t)(b * NN + n) * QK + qd] = acq;
  int w  = n >> 9;                 // wave (512 cols each)
  int m  = n & 511;
  int i  = (m & 255) >> 2;         // lane
  int jc = ((m < 256) ? 0 : 4) + (m & 3);
  int ev = qd >> 2, c = qd & 3;
  kt_ws[(((size_t)(b * 4 + w) * 4096) + (ev * 8 + jc) * 64 + i) * 4 + c] = ack;
}

// Kernel 2: one block = (batch, 8 rows), 256 threads. Thread (w,lane) owns
// cols {512w+4*lane+j} and {512w+256+4*lane+j}, j=0..3, for all 8 rows.
// GEMM: R13's ka/kb k-double-buffer. Epilogue: all 16 G float4s loaded into
// named registers (REGULAR loads -- keeps G's ~60MB of L3 hits; R15's nt
// loads forfeited them), one fence AFTER the loads only, so the compiler
// remains free to hoist G-load issue into the GEMM tail (the overlap R15's
// pre-fence destroyed). __launch_bounds__(256,2) raises the VGPR cap to 256
// so the allocator MATERIALIZES the prefetch (R14: default heuristic sank
// it, VGPR stuck at 100). GEMM-phase peak ~150, epilogue ~140: spill-free.
__global__ __launch_bounds__(256, 2) void attn_kernel(
    const float* __restrict__ G,
    const float* __restrict__ q_ws, const float* __restrict__ kt_ws,
    float* __restrict__ out) {
  const int tid = threadIdx.x;
  const int b = blockIdx.y;
  const int r0 = blockIdx.x * 8;
  const int w = tid >> 6, lane = tid & 63;

  __shared__ float q_lds[4][256];  // wave-private q tile copies (1 KB/wave)
  __shared__ float red[4][8];

  // ---- wave-private q copy (8 rows x 32 = 256 contiguous floats) ----
  {
    const float* qb = q_ws + ((size_t)b * NN + r0) * QK;
    *(float4*)&q_lds[w][4 * lane] = *(const float4*)&qb[4 * lane];
  }

  // ---- GEMM: acc[r][j] = q[r0+r] . k[col(w,lane,j)] ----
  float acc[8][8];
#pragma unroll
  for (int r = 0; r < 8; ++r)
#pragma unroll
    for (int j = 0; j < 8; ++j) acc[r][j] = 0.f;

  const float4* kt =
      (const float4*)kt_ws + (size_t)(b * 4 + w) * 4096 + lane;

  float4 ka[8], kb[8];
#pragma unroll
  for (int j = 0; j < 8; ++j) ka[j] = kt[j * 64];  // ev=0, lane-coalesced

#pragma unroll
  for (int ev = 0; ev < 8; ++ev) {
    if (ev < 7) {
#pragma unroll
      for (int j = 0; j < 8; ++j) kb[j] = kt[((ev + 1) * 8 + j) * 64];
    }
#pragma unroll
    for (int r = 0; r < 8; ++r) {
      float q4[4];
      *(float4*)q4 = *(const float4*)&q_lds[w][r * 32 + ev * 4];  // broadcast
#pragma unroll
      for (int j = 0; j < 8; ++j) {
        acc[r][j] = fmaf(q4[0], ka[j].x, acc[r][j]);
        acc[r][j] = fmaf(q4[1], ka[j].y, acc[r][j]);
        acc[r][j] = fmaf(q4[2], ka[j].z, acc[r][j]);
        acc[r][j] = fmaf(q4[3], ka[j].w, acc[r][j]);
      }
    }
#pragma unroll
    for (int j = 0; j < 8; ++j) ka[j] = kb[j];  // renamed away by unroll
  }

  // ---- epilogue: prefetch ALL G into registers (compiler may hoist the
  //      issue into the GEMM tail; loads are after the last k-load in
  //      program order, so k vmcnt-waits never count them) ----
  const float* gb = G + ((size_t)b * NN + r0) * NN + 512 * w + 4 * lane;
  float4 g0[8], g1[8];
#pragma unroll
  for (int r = 0; r < 8; ++r) {
    g0[r] = *(const float4*)(gb + (size_t)r * NN);
    g1[r] = *(const float4*)(gb + (size_t)r * NN + 256);
  }
  __builtin_amdgcn_sched_barrier(0);  // math stays below the loads

  float rsum[8];
#pragma unroll
  for (int r = 0; r < 8; ++r) {
    float gg[8];
    *(float4*)&gg[0] = g0[r];
    *(float4*)&gg[4] = g1[r];
    float sum = 0.f;
#pragma unroll
    for (int j = 0; j < 8; ++j) {
      float v = acc[r][j];
      v = v * v * gg[j];
      acc[r][j] = v;
      sum += v;
    }
#pragma unroll
    for (int off = 32; off >= 1; off >>= 1) sum += __shfl_xor(sum, off, 64);
    rsum[r] = sum;
  }

  // ---- cross-wave reduce ----
  if ((tid & 63) == 0) {
#pragma unroll
    for (int r = 0; r < 8; ++r) red[w][r] = rsum[r];
  }
  __syncthreads();

  float inv[8];
#pragma unroll
  for (int r = 0; r < 8; ++r) {
    float total = red[0][r] + red[1][r] + red[2][r] + red[3][r];
    inv[r] = 1.0f / (total + 1e-6f);
  }

  // ---- scale + coalesced non-temporal store ----
  float* ob = out + ((size_t)b * NN + r0) * NN + 512 * w + 4 * lane;
#pragma unroll
  for (int r = 0; r < 8; ++r) {
    f32x4 o0, o1;
    o0.x = acc[r][0] * inv[r]; o0.y = acc[r][1] * inv[r];
    o0.z = acc[r][2] * inv[r]; o0.w = acc[r][3] * inv[r];
    o1.x = acc[r][4] * inv[r]; o1.y = acc[r][5] * inv[r];
    o1.z = acc[r][6] * inv[r]; o1.w = acc[r][7] * inv[r];
    __builtin_nontemporal_store(o0, (f32x4*)(ob + (size_t)r * NN));
    __builtin_nontemporal_store(o1, (f32x4*)(ob + (size_t)r * NN + 256));
  }
}

extern "C" void kernel_launch(void* const* d_in, const int* in_sizes, int n_in,
                              void* d_out, int out_size, void* d_ws, size_t ws_size,
                              hipStream_t stream) {
  const float* s  = (const float*)d_in[0];
  const float* G  = (const float*)d_in[1];
  const float* Wq = (const float*)d_in[2];
  const float* Wk = (const float*)d_in[3];
  float* out = (float*)d_out;

  float* q_ws  = (float*)d_ws;                       // B*N*QK floats = 2 MB
  float* kt_ws = q_ws + (size_t)BB * NN * QK;        // another 2 MB

  qk_kernel<<<(BB * NN * QK) / 256, 256, 0, stream>>>(s, Wq, Wk, q_ws, kt_ws);

  dim3 grid(NN / 8, BB);
  attn_kernel<<<grid, 256, 0, stream>>>(G, q_ws, kt_ws, out);
}